// Round 1
// baseline (300.548 us; speedup 1.0000x reference)
//
#include <hip/hip_runtime.h>

#define QK_SCALE 0.17677669529663687f

typedef __attribute__((ext_vector_type(8))) short bf16x8;
typedef __attribute__((ext_vector_type(4))) short bf16x4;
typedef __attribute__((ext_vector_type(4))) float floatx4;

__device__ __forceinline__ unsigned short f2bf(float f) {
    unsigned int u = __float_as_uint(f);
    u += 0x7fffu + ((u >> 16) & 1u);   // round-to-nearest-even
    return (unsigned short)(u >> 16);
}

__device__ __forceinline__ bf16x8 ld8_2x4(const short* p) {  // 8B-aligned pair load
    union { bf16x8 v8; bf16x4 v4[2]; } u;
    u.v4[0] = *(const bf16x4*)p;
    u.v4[1] = *(const bf16x4*)(p + 4);
    return u.v8;
}

// ---- prep: bf16 weights + combined (mask + gathered rel-pos bias) table ----
// ws layout: [0, 131072) bytes: qkv_w bf16 (49152) then proj_w bf16 (16384)
//            [131072, ...): cm fp32 (64,4,49,49) = 2,458,624 bytes
__global__ __launch_bounds__(256) void prep_kernel(
    const float* __restrict__ qkv_w, const float* __restrict__ proj_w,
    const float* __restrict__ bias_table, const float* __restrict__ mask,
    unsigned short* __restrict__ wbf, float* __restrict__ cm)
{
    int g = blockIdx.x * 256 + threadIdx.x;
    if (g < 49152) {
        wbf[g] = f2bf(qkv_w[g]);
    } else if (g < 65536) {
        wbf[g] = f2bf(proj_w[g - 49152]);
    } else if (g < 680192) {
        int t = g - 65536;              // ((w*4+h)*49+i)*49+j
        int j = t % 49; int t2 = t / 49;
        int i = t2 % 49; int t3 = t2 / 49;
        int h = t3 & 3;  int wn = t3 >> 2;
        int idx = (i / 7 - j / 7 + 6) * 13 + (i % 7 - j % 7 + 6);
        cm[t] = mask[wn * 2401 + i * 49 + j] + bias_table[idx * 4 + h];
    }
}

// LDS map (shorts). Head h region base hq = h*6784 (13568 B):
//   q:  hq+0     64 rows x 36  (2304)     [dead after S MFMAs]
//   k:  hq+2304  64 rows x 36  (2304)     [dead after S MFMAs]
//   vT: hq+4608  32 rows x 68  (2176)
//   P:  hq+0     64 rows x 72  (4608)     [overlaps dead q+k exactly]
// xs/ao: offset 0, 64 rows x 136 (8704)   [time-sliced vs head regions, barriers]
// total 27136 shorts = 54272 B  -> 3 blocks/CU (3*54272 = 162816 <= 163840)
__global__ __launch_bounds__(256, 3) void winattn_mfma(
    const float* __restrict__ x,
    const float* __restrict__ qkv_b,
    const float* __restrict__ proj_b,
    const unsigned short* __restrict__ wbf,
    const float* __restrict__ cm,
    float* __restrict__ out)
{
    __shared__ __align__(16) short smem[27136];   // 54272 B

    const int tid  = threadIdx.x;
    const int lane = tid & 63;
    const int lid  = lane & 15;
    const int quad = lane >> 4;
    const int h    = tid >> 6;        // wave = head
    const int b    = blockIdx.x;
    const int w    = b & 63;
    const int hq   = h * 6784;

    // ---- Phase 0: stage x (49x128) fp32 -> bf16 LDS rows (pitch 136), pad rows zeroed ----
    {
        const float4* xg = (const float4*)(x + (size_t)b * 6272);
        for (int i = tid; i < 1568; i += 256) {       // 49*32 float4s
            int n = i >> 5, c4 = i & 31;
            float4 v = xg[i];
            ushort4 u;
            u.x = f2bf(v.x); u.y = f2bf(v.y); u.z = f2bf(v.z); u.w = f2bf(v.w);
            *(ushort4*)&smem[n * 136 + c4 * 4] = u;
        }
        ushort4 z; z.x = 0; z.y = 0; z.z = 0; z.w = 0;
        for (int i = tid; i < 510; i += 256)          // rows 49..63: 15*136/4 = 510
            *(ushort4*)&smem[49 * 136 + i * 4] = z;
    }
    __syncthreads();

    // ---- load full A tile (64x128) into registers: 16 frags ----
    bf16x8 ax[4][4];
    #pragma unroll
    for (int mt = 0; mt < 4; ++mt)
        #pragma unroll
        for (int kb = 0; kb < 4; ++kb)
            ax[mt][kb] = *(const bf16x8*)&smem[(mt * 16 + lid) * 136 + kb * 32 + quad * 8];
    __syncthreads();   // xs consumed; head regions may now be written

    const floatx4 z4 = {0.f, 0.f, 0.f, 0.f};

    // ---- QKV: wave h computes q,k,v cols [32h,32h+32) -- 6 N-tiles of 16 ----
    #pragma unroll
    for (int t = 0; t < 6; ++t) {
        const int cb = (t < 2) ? (h * 32 + t * 16)
                     : (t < 4) ? (128 + h * 32 + (t - 2) * 16)
                               : (256 + h * 32 + (t - 4) * 16);
        const unsigned short* wr = wbf + (size_t)(cb + lid) * 128 + quad * 8;
        floatx4 acc[4] = {z4, z4, z4, z4};
        #pragma unroll
        for (int kb = 0; kb < 4; ++kb) {
            bf16x8 bw = *(const bf16x8*)(wr + kb * 32);
            #pragma unroll
            for (int mt = 0; mt < 4; ++mt)
                acc[mt] = __builtin_amdgcn_mfma_f32_16x16x32_bf16(ax[mt][kb], bw, acc[mt], 0, 0, 0);
        }
        const float bias = qkv_b[cb + lid];
        #pragma unroll
        for (int mt = 0; mt < 4; ++mt) {
            #pragma unroll
            for (int r = 0; r < 4; ++r) {
                const int row = mt * 16 + quad * 4 + r;
                const float v = acc[mt][r] + bias;
                if (t < 2) {          // q (pre-scaled), pitch 36
                    smem[hq + row * 36 + t * 16 + lid] = (short)f2bf(v * QK_SCALE);
                } else if (t < 4) {   // k row-major, pitch 36
                    smem[hq + 2304 + row * 36 + (t - 2) * 16 + lid] = (short)f2bf(v);
                } else {              // v transposed: vT[d][token], pitch 68
                    smem[hq + 4608 + ((t - 4) * 16 + lid) * 68 + row] = (short)f2bf(v);
                }
            }
        }
    }

    // ---- S = q @ k^T  (per head, within wave; 16 MFMAs) ----
    bf16x8 aq[4], bk[4];
    #pragma unroll
    for (int mt = 0; mt < 4; ++mt)
        aq[mt] = ld8_2x4(&smem[hq + (mt * 16 + lid) * 36 + quad * 8]);
    #pragma unroll
    for (int nt = 0; nt < 4; ++nt)
        bk[nt] = ld8_2x4(&smem[hq + 2304 + (nt * 16 + lid) * 36 + quad * 8]);

    floatx4 sacc[4][4];
    #pragma unroll
    for (int mt = 0; mt < 4; ++mt)
        #pragma unroll
        for (int nt = 0; nt < 4; ++nt)
            sacc[mt][nt] = __builtin_amdgcn_mfma_f32_16x16x32_bf16(aq[mt], bk[nt], z4, 0, 0, 0);

    // ---- softmax in C-layout; write P (bf16, pitch 72) into dead q/k region ----
    float invs[4][4];
    const float* cmb = cm + (size_t)(w * 4 + h) * 2401;
    #pragma unroll
    for (int mt = 0; mt < 4; ++mt) {
        #pragma unroll
        for (int r = 0; r < 4; ++r) {
            const int row  = mt * 16 + quad * 4 + r;
            const int rowc = (row < 49) ? row : 48;
            float sv[4];
            #pragma unroll
            for (int nt = 0; nt < 4; ++nt) {
                const int col  = nt * 16 + lid;
                const int colc = (col < 49) ? col : 48;
                float val = sacc[mt][nt][r] + cmb[rowc * 49 + colc];
                sv[nt] = (col < 49) ? val : -1e30f;
            }
            float mx = fmaxf(fmaxf(sv[0], sv[1]), fmaxf(sv[2], sv[3]));
            #pragma unroll
            for (int d = 1; d < 16; d <<= 1) mx = fmaxf(mx, __shfl_xor(mx, d));
            float sum = 0.f;
            #pragma unroll
            for (int nt = 0; nt < 4; ++nt) { float p = __expf(sv[nt] - mx); sv[nt] = p; sum += p; }
            #pragma unroll
            for (int d = 1; d < 16; d <<= 1) sum += __shfl_xor(sum, d);
            invs[mt][r] = 1.f / sum;
            #pragma unroll
            for (int nt = 0; nt < 4; ++nt)
                smem[hq + row * 72 + nt * 16 + lid] = (short)f2bf(sv[nt]);
        }
    }

    // ---- O = P @ v  (16 MFMAs), scale rows by 1/sum ----
    bf16x8 bv[2][2];
    #pragma unroll
    for (int nt2 = 0; nt2 < 2; ++nt2)
        #pragma unroll
        for (int kb2 = 0; kb2 < 2; ++kb2)
            bv[nt2][kb2] = ld8_2x4(&smem[hq + 4608 + (nt2 * 16 + lid) * 68 + kb2 * 32 + quad * 8]);

    floatx4 oacc[4][2] = {{z4, z4}, {z4, z4}, {z4, z4}, {z4, z4}};
    #pragma unroll
    for (int mt = 0; mt < 4; ++mt) {
        #pragma unroll
        for (int kb2 = 0; kb2 < 2; ++kb2) {
            bf16x8 ap = *(const bf16x8*)&smem[hq + (mt * 16 + lid) * 72 + kb2 * 32 + quad * 8];
            #pragma unroll
            for (int nt2 = 0; nt2 < 2; ++nt2)
                oacc[mt][nt2] = __builtin_amdgcn_mfma_f32_16x16x32_bf16(ap, bv[nt2][kb2], oacc[mt][nt2], 0, 0, 0);
        }
    }

    __syncthreads();   // all O MFMAs done everywhere; P/vT/q/k dead -> ao may overwrite

    // ---- write attn-out (bf16) to ao (pitch 136, offset 0) ----
    #pragma unroll
    for (int mt = 0; mt < 4; ++mt)
        #pragma unroll
        for (int nt2 = 0; nt2 < 2; ++nt2)
            #pragma unroll
            for (int r = 0; r < 4; ++r) {
                const int row = mt * 16 + quad * 4 + r;
                smem[row * 136 + h * 32 + nt2 * 16 + lid] =
                    (short)f2bf(oacc[mt][nt2][r] * invs[mt][r]);
            }
    __syncthreads();

    // ---- proj: C2 = ao @ proj_w.T ; wave h -> cols [32h, 32h+32) ----
    bf16x8 aa[4][4];
    #pragma unroll
    for (int mt = 0; mt < 4; ++mt)
        #pragma unroll
        for (int kb = 0; kb < 4; ++kb)
            aa[mt][kb] = *(const bf16x8*)&smem[(mt * 16 + lid) * 136 + kb * 32 + quad * 8];

    float* outb = out + (size_t)b * 6272;
    #pragma unroll
    for (int nt = 0; nt < 2; ++nt) {
        const int cb = h * 32 + nt * 16;
        const unsigned short* wr = wbf + 49152 + (size_t)(cb + lid) * 128 + quad * 8;
        floatx4 acc[4] = {z4, z4, z4, z4};
        #pragma unroll
        for (int kb = 0; kb < 4; ++kb) {
            bf16x8 bw = *(const bf16x8*)(wr + kb * 32);
            #pragma unroll
            for (int mt = 0; mt < 4; ++mt)
                acc[mt] = __builtin_amdgcn_mfma_f32_16x16x32_bf16(aa[mt][kb], bw, acc[mt], 0, 0, 0);
        }
        const float pb = proj_b[cb + lid];
        #pragma unroll
        for (int mt = 0; mt < 4; ++mt)
            #pragma unroll
            for (int r = 0; r < 4; ++r) {
                const int row = mt * 16 + quad * 4 + r;
                if (row < 49)
                    outb[row * 128 + cb + lid] = acc[mt][r] + pb;
            }
    }
}

extern "C" void kernel_launch(void* const* d_in, const int* in_sizes, int n_in,
                              void* d_out, int out_size, void* d_ws, size_t ws_size,
                              hipStream_t stream) {
    (void)in_sizes; (void)n_in; (void)out_size; (void)ws_size;
    const float* x          = (const float*)d_in[0];
    const float* mask       = (const float*)d_in[1];
    const float* qkv_w      = (const float*)d_in[2];
    const float* qkv_b      = (const float*)d_in[3];
    const float* proj_w     = (const float*)d_in[4];
    const float* proj_b     = (const float*)d_in[5];
    const float* bias_table = (const float*)d_in[6];

    unsigned short* wbf = (unsigned short*)d_ws;                 // 131072 B
    float* cm           = (float*)((char*)d_ws + 131072);        // 2,458,624 B

    prep_kernel<<<2657, 256, 0, stream>>>(qkv_w, proj_w, bias_table, mask, wbf, cm);
    winattn_mfma<<<4096, 256, 0, stream>>>(x, qkv_b, proj_b, wbf, cm, (float*)d_out);
}

// Round 2
// 276.500 us; speedup vs baseline: 1.0870x; 1.0870x over previous
//
#include <hip/hip_runtime.h>

#define QK_SCALE 0.17677669529663687f

typedef __attribute__((ext_vector_type(8))) short bf16x8;
typedef __attribute__((ext_vector_type(4))) short bf16x4;
typedef __attribute__((ext_vector_type(2))) short bf16x2;
typedef __attribute__((ext_vector_type(4))) float floatx4;

__device__ __forceinline__ unsigned short f2bf(float f) {
    unsigned int u = __float_as_uint(f);
    u += 0x7fffu + ((u >> 16) & 1u);   // round-to-nearest-even
    return (unsigned short)(u >> 16);
}

__device__ __forceinline__ bf16x8 ld8_2x4(const short* p) {  // 8B-aligned pair load
    union { bf16x8 v8; bf16x4 v4[2]; } u;
    u.v4[0] = *(const bf16x4*)p;
    u.v4[1] = *(const bf16x4*)(p + 4);
    return u.v8;
}

__device__ __forceinline__ bf16x8 ld8_4x2(const short* p) {  // 4B-aligned quad load
    union { bf16x8 v8; bf16x2 v2[4]; } u;
    u.v2[0] = *(const bf16x2*)p;
    u.v2[1] = *(const bf16x2*)(p + 2);
    u.v2[2] = *(const bf16x2*)(p + 4);
    u.v2[3] = *(const bf16x2*)(p + 6);
    return u.v8;
}

// ---- prep: bf16 weights + combined (mask + gathered rel-pos bias) table ----
// ws layout: [0, 131072) bytes: qkv_w bf16 (49152 sh) then proj_w bf16 (16384 sh)
//            [131072, ...): cm2 fp32 tiled [w][h][row<49][lid<16][nt<4] = 3,211,264 B
//            cm2 cols nt*16+lid >= 49 hold -1e30 (softmax pad baked in)
__global__ __launch_bounds__(256) void prep_kernel(
    const float* __restrict__ qkv_w, const float* __restrict__ proj_w,
    const float* __restrict__ bias_table, const float* __restrict__ mask,
    unsigned short* __restrict__ wbf, float* __restrict__ cm2)
{
    int g = blockIdx.x * 256 + threadIdx.x;
    if (g < 49152) {
        wbf[g] = f2bf(qkv_w[g]);
    } else if (g < 65536) {
        wbf[g] = f2bf(proj_w[g - 49152]);
    } else if (g < 868352) {
        int t = g - 65536;              // ((((w*4+h)*49 + row)*16 + lid)*4 + nt)
        int nt  = t & 3;
        int lid = (t >> 2) & 15;
        int t2  = t >> 6;               // (w*4+h)*49 + row
        int row = t2 % 49;
        int wh  = t2 / 49;
        int h   = wh & 3;
        int w   = wh >> 2;
        int col = nt * 16 + lid;
        float v;
        if (col < 49) {
            int idx = (row / 7 - col / 7 + 6) * 13 + (row % 7 - col % 7 + 6);
            v = mask[w * 2401 + row * 49 + col] + bias_table[idx * 4 + h];
        } else {
            v = -1e30f;
        }
        cm2[t] = v;
    }
}

// LDS map (shorts). Head h region base hq = h*6528 (13056 B):
//   q:  hq+0     64 rows x 34  (2176)     [dead after S MFMAs]
//   k:  hq+2176  64 rows x 34  (2176)     [dead after S MFMAs]
//   vT: hq+4352  32 rows x 68  (2176)
//   P:  hq+0     64 rows x 68  (4352)     [overlaps dead q+k exactly]
// xs/ao: offset 0, 64 rows x 136 (8704)   [time-sliced vs head regions, barriers]
// total 26112 shorts = 52224 B -> 3 blocks/CU (ceil to 52 KiB, 3*52 = 156 <= 160)
__global__ __launch_bounds__(256, 3) void winattn_mfma(
    const float* __restrict__ x,
    const float* __restrict__ qkv_b,
    const float* __restrict__ proj_b,
    const unsigned short* __restrict__ wbf,
    const float* __restrict__ cm2,
    float* __restrict__ out)
{
    __shared__ __align__(16) short smem[26112];   // 52224 B

    const int tid  = threadIdx.x;
    const int lane = tid & 63;
    const int lid  = lane & 15;
    const int quad = lane >> 4;
    const int h    = tid >> 6;        // wave = head
    const int b    = blockIdx.x;
    const int w    = b & 63;
    const int hq   = h * 6528;

    // ---- Phase 0: stage x (49x128) fp32 -> bf16 LDS rows (pitch 136), pad rows zeroed ----
    {
        const float4* xg = (const float4*)(x + (size_t)b * 6272);
        for (int i = tid; i < 1568; i += 256) {       // 49*32 float4s
            int n = i >> 5, c4 = i & 31;
            float4 v = xg[i];
            ushort4 u;
            u.x = f2bf(v.x); u.y = f2bf(v.y); u.z = f2bf(v.z); u.w = f2bf(v.w);
            *(ushort4*)&smem[n * 136 + c4 * 4] = u;
        }
        ushort4 z; z.x = 0; z.y = 0; z.z = 0; z.w = 0;
        for (int i = tid; i < 510; i += 256)          // rows 49..63: 15*136/4 = 510
            *(ushort4*)&smem[49 * 136 + i * 4] = z;
    }
    __syncthreads();

    // ---- load full A tile (64x128) into registers: 16 frags ----
    bf16x8 ax[4][4];
    #pragma unroll
    for (int mt = 0; mt < 4; ++mt)
        #pragma unroll
        for (int kb = 0; kb < 4; ++kb)
            ax[mt][kb] = *(const bf16x8*)&smem[(mt * 16 + lid) * 136 + kb * 32 + quad * 8];
    __syncthreads();   // xs consumed; head regions may now be written

    const floatx4 z4 = {0.f, 0.f, 0.f, 0.f};

    // ---- QKV: wave h computes q,k,v cols [32h,32h+32) -- 6 N-tiles of 16 ----
    #pragma unroll
    for (int t = 0; t < 6; ++t) {
        const int cb = (t < 2) ? (h * 32 + t * 16)
                     : (t < 4) ? (128 + h * 32 + (t - 2) * 16)
                               : (256 + h * 32 + (t - 4) * 16);
        const unsigned short* wr = wbf + (size_t)(cb + lid) * 128 + quad * 8;
        floatx4 acc[4] = {z4, z4, z4, z4};
        #pragma unroll
        for (int kb = 0; kb < 4; ++kb) {
            bf16x8 bw = *(const bf16x8*)(wr + kb * 32);
            #pragma unroll
            for (int mt = 0; mt < 4; ++mt)
                acc[mt] = __builtin_amdgcn_mfma_f32_16x16x32_bf16(ax[mt][kb], bw, acc[mt], 0, 0, 0);
        }
        const float bias = qkv_b[cb + lid];
        #pragma unroll
        for (int mt = 0; mt < 4; ++mt) {
            #pragma unroll
            for (int r = 0; r < 4; ++r) {
                const int row = mt * 16 + quad * 4 + r;
                const float v = acc[mt][r] + bias;
                if (t < 2) {          // q (pre-scaled), pitch 34
                    smem[hq + row * 34 + t * 16 + lid] = (short)f2bf(v * QK_SCALE);
                } else if (t < 4) {   // k row-major, pitch 34
                    smem[hq + 2176 + row * 34 + (t - 2) * 16 + lid] = (short)f2bf(v);
                } else {              // v transposed: vT[d][token], pitch 68
                    smem[hq + 4352 + ((t - 4) * 16 + lid) * 68 + row] = (short)f2bf(v);
                }
            }
        }
    }

    // ---- prefetch cm2 slab for mt=0 (L2 latency hides under S-phase) ----
    const float4* cm2b = (const float4*)cm2 + ((size_t)(w * 4 + h) * 49) * 16 + lid;
    float4 cmv[4][4];
    #pragma unroll
    for (int r = 0; r < 4; ++r)
        cmv[0][r] = cm2b[(quad * 4 + r) * 16];     // rows 0..15, no clamp needed

    // ---- S = q @ k^T  (per head, within wave; 16 MFMAs) ----
    bf16x8 aq[4], bk[4];
    #pragma unroll
    for (int mt = 0; mt < 4; ++mt)
        aq[mt] = ld8_4x2(&smem[hq + (mt * 16 + lid) * 34 + quad * 8]);
    #pragma unroll
    for (int nt = 0; nt < 4; ++nt)
        bk[nt] = ld8_4x2(&smem[hq + 2176 + (nt * 16 + lid) * 34 + quad * 8]);

    floatx4 sacc[4][4];
    #pragma unroll
    for (int mt = 0; mt < 4; ++mt)
        #pragma unroll
        for (int nt = 0; nt < 4; ++nt)
            sacc[mt][nt] = __builtin_amdgcn_mfma_f32_16x16x32_bf16(aq[mt], bk[nt], z4, 0, 0, 0);

    // ---- softmax in C-layout; write P (bf16, pitch 68) into dead q/k region ----
    // cm2 has -1e30 baked into cols >= 49, so no col clamp/select needed.
    float invs[4][4];
    #pragma unroll
    for (int mt = 0; mt < 4; ++mt) {
        if (mt < 3) {   // prefetch next slab while computing this one
            #pragma unroll
            for (int r = 0; r < 4; ++r) {
                const int row  = (mt + 1) * 16 + quad * 4 + r;
                const int rowc = (row < 49) ? row : 48;
                cmv[mt + 1][r] = cm2b[rowc * 16];
            }
        }
        #pragma unroll
        for (int r = 0; r < 4; ++r) {
            const int row = mt * 16 + quad * 4 + r;
            float sv[4];
            #pragma unroll
            for (int nt = 0; nt < 4; ++nt)
                sv[nt] = sacc[mt][nt][r] + cmv[mt][r][nt];
            float mx = fmaxf(fmaxf(sv[0], sv[1]), fmaxf(sv[2], sv[3]));
            #pragma unroll
            for (int d = 1; d < 16; d <<= 1) mx = fmaxf(mx, __shfl_xor(mx, d));
            float sum = 0.f;
            #pragma unroll
            for (int nt = 0; nt < 4; ++nt) { float p = __expf(sv[nt] - mx); sv[nt] = p; sum += p; }
            #pragma unroll
            for (int d = 1; d < 16; d <<= 1) sum += __shfl_xor(sum, d);
            invs[mt][r] = 1.f / sum;
            #pragma unroll
            for (int nt = 0; nt < 4; ++nt)
                smem[hq + row * 68 + nt * 16 + lid] = (short)f2bf(sv[nt]);
        }
    }

    // ---- O = P @ v  (16 MFMAs), scale rows by 1/sum ----
    bf16x8 bv[2][2];
    #pragma unroll
    for (int nt2 = 0; nt2 < 2; ++nt2)
        #pragma unroll
        for (int kb2 = 0; kb2 < 2; ++kb2)
            bv[nt2][kb2] = ld8_2x4(&smem[hq + 4352 + (nt2 * 16 + lid) * 68 + kb2 * 32 + quad * 8]);

    floatx4 oacc[4][2] = {{z4, z4}, {z4, z4}, {z4, z4}, {z4, z4}};
    #pragma unroll
    for (int mt = 0; mt < 4; ++mt) {
        #pragma unroll
        for (int kb2 = 0; kb2 < 2; ++kb2) {
            bf16x8 ap = ld8_2x4(&smem[hq + (mt * 16 + lid) * 68 + kb2 * 32 + quad * 8]);
            #pragma unroll
            for (int nt2 = 0; nt2 < 2; ++nt2)
                oacc[mt][nt2] = __builtin_amdgcn_mfma_f32_16x16x32_bf16(ap, bv[nt2][kb2], oacc[mt][nt2], 0, 0, 0);
        }
    }

    __syncthreads();   // all O MFMAs done everywhere; P/vT/q/k dead -> ao may overwrite

    // ---- write attn-out (bf16) to ao (pitch 136, offset 0) ----
    #pragma unroll
    for (int mt = 0; mt < 4; ++mt)
        #pragma unroll
        for (int nt2 = 0; nt2 < 2; ++nt2)
            #pragma unroll
            for (int r = 0; r < 4; ++r) {
                const int row = mt * 16 + quad * 4 + r;
                smem[row * 136 + h * 32 + nt2 * 16 + lid] =
                    (short)f2bf(oacc[mt][nt2][r] * invs[mt][r]);
            }
    __syncthreads();

    // ---- proj: C2 = ao @ proj_w.T ; wave h -> cols [32h, 32h+32) ----
    bf16x8 aa[4][4];
    #pragma unroll
    for (int mt = 0; mt < 4; ++mt)
        #pragma unroll
        for (int kb = 0; kb < 4; ++kb)
            aa[mt][kb] = *(const bf16x8*)&smem[(mt * 16 + lid) * 136 + kb * 32 + quad * 8];

    float* outb = out + (size_t)b * 6272;
    #pragma unroll
    for (int nt = 0; nt < 2; ++nt) {
        const int cb = h * 32 + nt * 16;
        const unsigned short* wr = wbf + 49152 + (size_t)(cb + lid) * 128 + quad * 8;
        floatx4 acc[4] = {z4, z4, z4, z4};
        #pragma unroll
        for (int kb = 0; kb < 4; ++kb) {
            bf16x8 bw = *(const bf16x8*)(wr + kb * 32);
            #pragma unroll
            for (int mt = 0; mt < 4; ++mt)
                acc[mt] = __builtin_amdgcn_mfma_f32_16x16x32_bf16(aa[mt][kb], bw, acc[mt], 0, 0, 0);
        }
        const float pb = proj_b[cb + lid];
        #pragma unroll
        for (int mt = 0; mt < 4; ++mt)
            #pragma unroll
            for (int r = 0; r < 4; ++r) {
                const int row = mt * 16 + quad * 4 + r;
                if (row < 49)
                    outb[row * 128 + cb + lid] = acc[mt][r] + pb;
            }
    }
}

extern "C" void kernel_launch(void* const* d_in, const int* in_sizes, int n_in,
                              void* d_out, int out_size, void* d_ws, size_t ws_size,
                              hipStream_t stream) {
    (void)in_sizes; (void)n_in; (void)out_size; (void)ws_size;
    const float* x          = (const float*)d_in[0];
    const float* mask       = (const float*)d_in[1];
    const float* qkv_w      = (const float*)d_in[2];
    const float* qkv_b      = (const float*)d_in[3];
    const float* proj_w     = (const float*)d_in[4];
    const float* proj_b     = (const float*)d_in[5];
    const float* bias_table = (const float*)d_in[6];

    unsigned short* wbf = (unsigned short*)d_ws;                 // 131072 B
    float* cm2          = (float*)((char*)d_ws + 131072);        // 3,211,264 B

    prep_kernel<<<3392, 256, 0, stream>>>(qkv_w, proj_w, bias_table, mask, wbf, cm2);
    winattn_mfma<<<4096, 256, 0, stream>>>(x, qkv_b, proj_b, wbf, cm2, (float*)d_out);
}